// Round 9
// baseline (210.357 us; speedup 1.0000x reference)
//
#include <hip/hip_runtime.h>
#include <hip/hip_bf16.h>
#include <stdint.h>

#define D_MODEL 1024
#define N_HEADS 16
#define HEAD_DIM 64
#define KV_HEADS 4
#define BATCH 2
#define SEQ 2048
#define MROWS (BATCH * SEQ)      // 4096
#define LDQK 1280                // Q|K row stride (V lives in VtG)

typedef __attribute__((ext_vector_type(8))) short bf16x8;
typedef __attribute__((ext_vector_type(4))) short short4v;
typedef __attribute__((ext_vector_type(4))) float f32x4;

// f32 -> bf16 RNE via native cast (compiler can fuse pairs to v_cvt_pk_bf16_f32)
__device__ __forceinline__ short f2bf(float f) {
    __hip_bfloat16 h = __float2bfloat16(f);
    return *reinterpret_cast<short*>(&h);
}
__device__ __forceinline__ unsigned pack_bf16(float a, float b) {
    unsigned short ua = (unsigned short)f2bf(a);
    unsigned short ub = (unsigned short)f2bf(b);
    return (unsigned)ua | ((unsigned)ub << 16);
}

// ---------------------------------------------------------------------------
// fp32 -> bf16 elementwise
// ---------------------------------------------------------------------------
__global__ __launch_bounds__(256) void convert_bf16_kernel(
    const float* __restrict__ in, short* __restrict__ out, int n4)
{
    int i = blockIdx.x * 256 + threadIdx.x;
    if (i < n4) {
        float4 v = ((const float4*)in)[i];
        short4v o;
        o.x = f2bf(v.x); o.y = f2bf(v.y); o.z = f2bf(v.z); o.w = f2bf(v.w);
        ((short4v*)out)[i] = o;
    }
}

// ---------------------------------------------------------------------------
// Fused weight prep: z<4 -> transpose W_z [1024][N] fp32 into dst [N][1024]
// bf16; z==4 -> bias concat.
// ---------------------------------------------------------------------------
__global__ __launch_bounds__(256) void prep_kernel(
    const float* __restrict__ Wq, const float* __restrict__ Wk,
    const float* __restrict__ Wv, const float* __restrict__ Wo,
    const float* __restrict__ bq, const float* __restrict__ bk,
    const float* __restrict__ bv,
    short* __restrict__ BtQKV, short* __restrict__ WoT,
    float* __restrict__ bcat)
{
    const int z = blockIdx.z;
    const int t = threadIdx.x;
    if (z == 4) {
        if (blockIdx.y == 0 && blockIdx.x < 6) {
            int n = blockIdx.x * 256 + t;
            bcat[n] = n < 1024 ? bq[n] : (n < 1280 ? bk[n - 1024] : bv[n - 1280]);
        }
        return;
    }
    const float* src; short* dst; int N;
    switch (z) {
        case 0:  src = Wq; dst = BtQKV;                       N = 1024; break;
        case 1:  src = Wk; dst = BtQKV + (size_t)1024 * 1024; N = 256;  break;
        case 2:  src = Wv; dst = BtQKV + (size_t)1280 * 1024; N = 256;  break;
        default: src = Wo; dst = WoT;                         N = 1024; break;
    }
    const int n0 = blockIdx.x * 64;
    if (n0 >= N) return;
    const int k0 = blockIdx.y * 64;
    __shared__ short Ts[64][68];
    const int r = t >> 4, c4 = (t & 15) * 4;
    #pragma unroll
    for (int i = 0; i < 4; ++i) {
        int k = r + i * 16;
        float4 v = *(const float4*)(src + (size_t)(k0 + k) * N + n0 + c4);
        Ts[c4 + 0][k] = f2bf(v.x);
        Ts[c4 + 1][k] = f2bf(v.y);
        Ts[c4 + 2][k] = f2bf(v.z);
        Ts[c4 + 3][k] = f2bf(v.w);
    }
    __syncthreads();
    #pragma unroll
    for (int i = 0; i < 4; ++i) {
        int n = r + i * 16;
        short4v o = *(short4v*)&Ts[n][c4];
        *(short4v*)(dst + (size_t)(n0 + n) * 1024 + k0 + c4) = o;
    }
}

// ---------------------------------------------------------------------------
// bf16 MFMA GEMM: C[M,N] = A[M,1024] @ Bt[N,1024]^T + bias[N]
// Tile 128x64, BK=64, 4 waves (2x2 grid, 64x32 out each). Reg-staged + XOR
// slot-swizzle. BN=64 (was 128): QKV grid 768 blocks = 3/CU, O-proj 512 = 2/CU
// (was 1-1.5/CU -> 1 wave/SIMD, fully stall-exposed; G1 grid starvation).
// Epilogue: QKV V-region blocks (bn>=1280) write V^T to VtG.
// ---------------------------------------------------------------------------
template <bool BF16_OUT>
__global__ __launch_bounds__(256) void gemm_kernel(
    const short* __restrict__ A, const short* __restrict__ Bt,
    const float* __restrict__ bias, void* __restrict__ Cv,
    short* __restrict__ VtG, int ldc)
{
    __shared__ short As[128 * 64];
    __shared__ short Bs[64 * 64];
    const int t = threadIdx.x;
    const int l = t & 63;
    const int w = t >> 6;
    const int bm = blockIdx.y * 128, bn = blockIdx.x * 64;
    const int wr = (w >> 1) * 64, wc = (w & 1) * 32;
    const int lr = l & 15, lg = l >> 4;

    f32x4 acc[4][2] = {};
    bf16x8 ra[4], rb[2];

    #pragma unroll
    for (int i = 0; i < 4; ++i) {
        int u = t + 256 * i, row = u >> 3, s = u & 7;
        ra[i] = *(const bf16x8*)(A + (size_t)(bm + row) * 1024 + s * 8);
    }
    #pragma unroll
    for (int i = 0; i < 2; ++i) {
        int u = t + 256 * i, row = u >> 3, s = u & 7;
        rb[i] = *(const bf16x8*)(Bt + (size_t)(bn + row) * 1024 + s * 8);
    }

    for (int k0 = 0; k0 < 1024; k0 += 64) {
        __syncthreads();
        #pragma unroll
        for (int i = 0; i < 4; ++i) {
            int u = t + 256 * i, row = u >> 3, s = u & 7;
            *(bf16x8*)(&As[row * 64 + (s ^ (row & 7)) * 8]) = ra[i];
        }
        #pragma unroll
        for (int i = 0; i < 2; ++i) {
            int u = t + 256 * i, row = u >> 3, s = u & 7;
            *(bf16x8*)(&Bs[row * 64 + (s ^ (row & 7)) * 8]) = rb[i];
        }
        if (k0 + 64 < 1024) {
            #pragma unroll
            for (int i = 0; i < 4; ++i) {
                int u = t + 256 * i, row = u >> 3, s = u & 7;
                ra[i] = *(const bf16x8*)(A + (size_t)(bm + row) * 1024 + k0 + 64 + s * 8);
            }
            #pragma unroll
            for (int i = 0; i < 2; ++i) {
                int u = t + 256 * i, row = u >> 3, s = u & 7;
                rb[i] = *(const bf16x8*)(Bt + (size_t)(bn + row) * 1024 + k0 + 64 + s * 8);
            }
        }
        __syncthreads();
        #pragma unroll
        for (int tt = 0; tt < 2; ++tt) {
            bf16x8 af[4], bfr[2];
            #pragma unroll
            for (int mi = 0; mi < 4; ++mi) {
                int m = wr + mi * 16 + lr;
                af[mi] = *(const bf16x8*)(&As[m * 64 + ((tt * 4 + lg) ^ (m & 7)) * 8]);
            }
            #pragma unroll
            for (int ni = 0; ni < 2; ++ni) {
                int n = wc + ni * 16 + lr;
                bfr[ni] = *(const bf16x8*)(&Bs[n * 64 + ((tt * 4 + lg) ^ (n & 7)) * 8]);
            }
            #pragma unroll
            for (int mi = 0; mi < 4; ++mi)
                #pragma unroll
                for (int ni = 0; ni < 2; ++ni)
                    acc[mi][ni] = __builtin_amdgcn_mfma_f32_16x16x32_bf16(
                        af[mi], bfr[ni], acc[mi][ni], 0, 0, 0);
        }
    }

    if constexpr (BF16_OUT) {
        if (bn >= 1280) {          // V-region: write V^T[b][kvh][d][kv]
            #pragma unroll
            for (int ni = 0; ni < 2; ++ni) {
                int n = bn + wc + ni * 16 + lr;
                int vcol = n - 1280, kvh = vcol >> 6, d = vcol & 63;
                float bv = bias[n];
                #pragma unroll
                for (int mi = 0; mi < 4; ++mi) {
                    int m = bm + wr + mi * 16 + lg * 4;
                    int b = m >> 11, kv = m & 2047;
                    short4v ov;
                    ov.x = f2bf(acc[mi][ni][0] + bv);
                    ov.y = f2bf(acc[mi][ni][1] + bv);
                    ov.z = f2bf(acc[mi][ni][2] + bv);
                    ov.w = f2bf(acc[mi][ni][3] + bv);
                    *(short4v*)(VtG + ((size_t)(b * 4 + kvh) * 64 + d) * 2048 + kv) = ov;
                }
            }
            return;
        }
    }
    #pragma unroll
    for (int ni = 0; ni < 2; ++ni) {
        int n = bn + wc + ni * 16 + lr;
        float bv = bias[n];
        #pragma unroll
        for (int mi = 0; mi < 4; ++mi) {
            #pragma unroll
            for (int r = 0; r < 4; ++r) {
                int m = bm + wr + mi * 16 + lg * 4 + r;
                float v = acc[mi][ni][r] + bv;
                if constexpr (BF16_OUT)
                    ((short*)Cv)[(size_t)m * ldc + n] = f2bf(v);
                else
                    ((float*)Cv)[(size_t)m * ldc + n] = v;
            }
        }
    }
}

// ---------------------------------------------------------------------------
// Flash causal GQA attention — swapped QK^T (S^T = K·Q^T), lane-local softmax,
// defer-max, V^T staged from global VtG.
// UN-PAIRED + LPT: qb = 31 - blockIdx.x so the longest blocks (32 kv-iters)
// dispatch FIRST; short blocks land last and fill draining CUs. 1024 blocks =
// 4/CU = 16 waves/CU (2x the paired config; round-4's tail was longest-LAST).
// ---------------------------------------------------------------------------
__global__ __launch_bounds__(256) void attn_kernel(
    const short* __restrict__ QK, const short* __restrict__ VtG,
    short* __restrict__ Aout)
{
    __shared__ short Qs[64 * 64];
    __shared__ short Ks[64 * 64];
    __shared__ short Vt[64 * 64];
    __shared__ short Ps[4 * 16 * 64];     // per-wave private P tiles

    const int t = threadIdx.x, l = t & 63, w = t >> 6;
    const int h = blockIdx.y, b = blockIdx.z;
    const int kvh = h >> 2;               // jnp.repeat: h // N_GROUPS
    const int lr = l & 15, lg = l >> 4;
    const float SCL = 0.125f * 1.44269504f;   // 1/sqrt(64) * log2(e)

    const size_t baseQ  = (size_t)(b * SEQ) * LDQK + h * 64;
    const size_t baseK  = (size_t)(b * SEQ) * LDQK + 1024 + kvh * 64;
    const size_t baseVt = (size_t)(b * 4 + kvh) * (64 * 2048);

    const int qb = 31 - (int)blockIdx.x;   // LPT: longest first
    const int q0 = qb * 64;

    // ---- stage Q tile (swizzled) ----
    #pragma unroll
    for (int i = 0; i < 2; ++i) {
        int u = t + 256 * i, row = u >> 3, s = u & 7;
        bf16x8 v = *(const bf16x8*)(QK + baseQ + (size_t)(q0 + row) * LDQK + s * 8);
        *(bf16x8*)(&Qs[row * 64 + (s ^ (row & 7)) * 8]) = v;
    }
    // ---- prefetch K, V^T tile kb=0 ----
    bf16x8 rk[2], rv[2];
    #pragma unroll
    for (int i = 0; i < 2; ++i) {
        int u = t + 256 * i, row = u >> 3, s = u & 7;
        rk[i] = *(const bf16x8*)(QK + baseK + (size_t)row * LDQK + s * 8);
        rv[i] = *(const bf16x8*)(VtG + baseVt + (size_t)row * 2048 + s * 8);
    }
    __syncthreads();

    // ---- Q fragments (B-operand: lane holds q=lane&15, d-chunk lg*8) ----
    bf16x8 qf[2];
    #pragma unroll
    for (int tt = 0; tt < 2; ++tt) {
        int q = w * 16 + lr;
        qf[tt] = *(const bf16x8*)(&Qs[q * 64 + ((tt * 4 + lg) ^ (lr & 7)) * 8]);
    }

    float m_i = -INFINITY, l_i = 0.f;
    f32x4 o[4];
    #pragma unroll
    for (int ni = 0; ni < 4; ++ni) o[ni] = (f32x4){0.f, 0.f, 0.f, 0.f};

    const int qg = q0 + w * 16 + lr;   // this lane's global q row

    for (int kb = 0; kb <= qb; ++kb) {
        __syncthreads();
        // ---- commit staged K and V^T (both plain b128, swizzled) ----
        #pragma unroll
        for (int i = 0; i < 2; ++i) {
            int u = t + 256 * i, row = u >> 3, s = u & 7;
            *(bf16x8*)(&Ks[row * 64 + (s ^ (row & 7)) * 8]) = rk[i];
            *(bf16x8*)(&Vt[row * 64 + (s ^ (row & 7)) * 8]) = rv[i];
        }
        // ---- prefetch next K,V^T (in flight under this iter's compute) ----
        if (kb < qb) {
            int kn = (kb + 1) * 64;
            #pragma unroll
            for (int i = 0; i < 2; ++i) {
                int u = t + 256 * i, row = u >> 3, s = u & 7;
                rk[i] = *(const bf16x8*)(QK + baseK + (size_t)(kn + row) * LDQK + s * 8);
                rv[i] = *(const bf16x8*)(VtG + baseVt + (size_t)row * 2048 + kn + s * 8);
            }
        }
        __syncthreads();

        // ---- S^T = K @ Q^T : lane holds q=lr, kv = ni*16 + lg*4 + r ----
        f32x4 sf[4];
        #pragma unroll
        for (int ni = 0; ni < 4; ++ni) sf[ni] = (f32x4){0.f, 0.f, 0.f, 0.f};
        __builtin_amdgcn_s_setprio(1);
        #pragma unroll
        for (int tt = 0; tt < 2; ++tt) {
            #pragma unroll
            for (int ni = 0; ni < 4; ++ni) {
                int kvr = ni * 16 + lr;
                bf16x8 kf = *(const bf16x8*)(&Ks[kvr * 64 + ((tt * 4 + lg) ^ (lr & 7)) * 8]);
                sf[ni] = __builtin_amdgcn_mfma_f32_16x16x32_bf16(kf, qf[tt], sf[ni], 0, 0, 0);
            }
        }
        __builtin_amdgcn_s_setprio(0);

        // ---- scale (+ causal mask on diagonal tile only) ----
        float p[4][4];
        #pragma unroll
        for (int ni = 0; ni < 4; ++ni)
            #pragma unroll
            for (int r = 0; r < 4; ++r)
                p[ni][r] = sf[ni][r] * SCL;
        if (kb == qb) {
            #pragma unroll
            for (int ni = 0; ni < 4; ++ni)
                #pragma unroll
                for (int r = 0; r < 4; ++r)
                    if (kb * 64 + ni * 16 + lg * 4 + r > qg)
                        p[ni][r] = -INFINITY;
        }

        // ---- lane-local online softmax with defer-max (THR=8 log2) ----
        float rm = fmaxf(fmaxf(fmaxf(p[0][0], p[0][1]), fmaxf(p[0][2], p[0][3])),
                         fmaxf(fmaxf(p[1][0], p[1][1]), fmaxf(p[1][2], p[1][3])));
        rm = fmaxf(rm, fmaxf(fmaxf(fmaxf(p[2][0], p[2][1]), fmaxf(p[2][2], p[2][3])),
                             fmaxf(fmaxf(p[3][0], p[3][1]), fmaxf(p[3][2], p[3][3]))));
        rm = fmaxf(rm, __shfl_xor(rm, 16));
        rm = fmaxf(rm, __shfl_xor(rm, 32));
        if (__any(rm > m_i + 8.0f)) {
            float mnew = fmaxf(m_i, rm);
            float corr = exp2f(m_i - mnew);   // 0 on first tile
            l_i *= corr;
            #pragma unroll
            for (int ni = 0; ni < 4; ++ni) o[ni] *= corr;
            m_i = mnew;
        }
        float rs = 0.f;
        #pragma unroll
        for (int ni = 0; ni < 4; ++ni) {
            #pragma unroll
            for (int r = 0; r < 4; ++r) {
                float pv = exp2f(p[ni][r] - m_i);
                p[ni][r] = pv;
                rs += pv;
            }
            // pack P (4 bf16 = 8B single store) into swizzled Ps[q][kv]
            int slot = (ni * 2 + (lg >> 1)) ^ (lr & 7);
            uint2 pk;
            pk.x = pack_bf16(p[ni][0], p[ni][1]);
            pk.y = pack_bf16(p[ni][2], p[ni][3]);
            *(uint2*)(&Ps[w * 1024 + lr * 64 + slot * 8 + (lg & 1) * 4]) = pk;
        }
        rs += __shfl_xor(rs, 16);
        rs += __shfl_xor(rs, 32);
        l_i += rs;

        // ---- O^T += V^T @ P^T ----
        __builtin_amdgcn_s_setprio(1);
        #pragma unroll
        for (int tt = 0; tt < 2; ++tt) {
            bf16x8 pf = *(const bf16x8*)(&Ps[w * 1024 + lr * 64 + ((tt * 4 + lg) ^ (lr & 7)) * 8]);
            #pragma unroll
            for (int ni = 0; ni < 4; ++ni) {
                int d = ni * 16 + lr;
                bf16x8 vf = *(const bf16x8*)(&Vt[d * 64 + ((tt * 4 + lg) ^ (lr & 7)) * 8]);
                o[ni] = __builtin_amdgcn_mfma_f32_16x16x32_bf16(vf, pf, o[ni], 0, 0, 0);
            }
        }
        __builtin_amdgcn_s_setprio(0);
    }

    // ---- normalize + store (lane writes 4x 8B runs on its q row) ----
    float inv = 1.0f / l_i;
    const size_t orow = (size_t)(b * SEQ + qg) * D_MODEL + h * 64;
    #pragma unroll
    for (int ni = 0; ni < 4; ++ni) {
        short4v ov;
        ov.x = f2bf(o[ni][0] * inv);
        ov.y = f2bf(o[ni][1] * inv);
        ov.z = f2bf(o[ni][2] * inv);
        ov.w = f2bf(o[ni][3] * inv);
        *(short4v*)(Aout + orow + ni * 16 + lg * 4) = ov;
    }
}

// ---------------------------------------------------------------------------
extern "C" void kernel_launch(void* const* d_in, const int* in_sizes, int n_in,
                              void* d_out, int out_size, void* d_ws, size_t ws_size,
                              hipStream_t stream) {
    const float* x  = (const float*)d_in[0];
    const float* Wq = (const float*)d_in[1];
    const float* bq = (const float*)d_in[2];
    const float* Wk = (const float*)d_in[3];
    const float* bk = (const float*)d_in[4];
    const float* Wv = (const float*)d_in[5];
    const float* bv = (const float*)d_in[6];
    const float* Wo = (const float*)d_in[7];
    const float* bo = (const float*)d_in[8];
    float* out = (float*)d_out;

    // ws (shorts): xb | BtQKV | WoT | QK(stride1280) | VtG | Abuf | bcat(f32)
    short* xb    = (short*)d_ws;
    short* BtQKV = xb    + (size_t)MROWS * D_MODEL;
    short* WoT   = BtQKV + (size_t)1536 * 1024;
    short* QKbuf = WoT   + (size_t)1024 * 1024;
    short* VtG   = QKbuf + (size_t)MROWS * LDQK;
    short* Abuf  = VtG   + (size_t)BATCH * KV_HEADS * 64 * 2048;
    float* bcat  = (float*)(Abuf + (size_t)MROWS * D_MODEL);

    dim3 blk(256);
    convert_bf16_kernel<<<dim3(MROWS * D_MODEL / 4 / 256), blk, 0, stream>>>(
        x, xb, MROWS * D_MODEL / 4);
    prep_kernel<<<dim3(16, 16, 5), blk, 0, stream>>>(
        Wq, Wk, Wv, Wo, bq, bk, bv, BtQKV, WoT, bcat);
    // fused QKV projection (BN=64): Q,K -> QKbuf (ldc=1280); V -> VtG transposed
    gemm_kernel<true><<<dim3(24, MROWS / 128), blk, 0, stream>>>(
        xb, BtQKV, bcat, QKbuf, VtG, LDQK);
    attn_kernel<<<dim3(32, N_HEADS, BATCH), blk, 0, stream>>>(QKbuf, VtG, Abuf);
    gemm_kernel<false><<<dim3(16, MROWS / 128), blk, 0, stream>>>(
        Abuf, WoT, bo, out, nullptr, 1024);
}

// Round 11
// 182.858 us; speedup vs baseline: 1.1504x; 1.1504x over previous
//
#include <hip/hip_runtime.h>
#include <hip/hip_bf16.h>
#include <stdint.h>

#define D_MODEL 1024
#define N_HEADS 16
#define HEAD_DIM 64
#define KV_HEADS 4
#define BATCH 2
#define SEQ 2048
#define MROWS (BATCH * SEQ)      // 4096
#define LDQK 1280                // Q|K row stride (V lives in VtG)

typedef __attribute__((ext_vector_type(8))) short bf16x8;
typedef __attribute__((ext_vector_type(4))) short short4v;
typedef __attribute__((ext_vector_type(4))) float f32x4;

// f32 -> bf16 RNE via native cast (compiler fuses pairs to v_cvt_pk_bf16_f32)
__device__ __forceinline__ short f2bf(float f) {
    __hip_bfloat16 h = __float2bfloat16(f);
    return *reinterpret_cast<short*>(&h);
}
__device__ __forceinline__ unsigned pack_bf16(float a, float b) {
    unsigned short ua = (unsigned short)f2bf(a);
    unsigned short ub = (unsigned short)f2bf(b);
    return (unsigned)ua | ((unsigned)ub << 16);
}

// ---------------------------------------------------------------------------
// fp32 -> bf16 elementwise
// ---------------------------------------------------------------------------
__global__ __launch_bounds__(256) void convert_bf16_kernel(
    const float* __restrict__ in, short* __restrict__ out, int n4)
{
    int i = blockIdx.x * 256 + threadIdx.x;
    if (i < n4) {
        float4 v = ((const float4*)in)[i];
        short4v o;
        o.x = f2bf(v.x); o.y = f2bf(v.y); o.z = f2bf(v.z); o.w = f2bf(v.w);
        ((short4v*)out)[i] = o;
    }
}

// ---------------------------------------------------------------------------
// Fused weight prep: z<4 -> transpose W_z [1024][N] fp32 into dst [N][1024]
// bf16; z==4 -> bias concat.
// ---------------------------------------------------------------------------
__global__ __launch_bounds__(256) void prep_kernel(
    const float* __restrict__ Wq, const float* __restrict__ Wk,
    const float* __restrict__ Wv, const float* __restrict__ Wo,
    const float* __restrict__ bq, const float* __restrict__ bk,
    const float* __restrict__ bv,
    short* __restrict__ BtQKV, short* __restrict__ WoT,
    float* __restrict__ bcat)
{
    const int z = blockIdx.z;
    const int t = threadIdx.x;
    if (z == 4) {
        if (blockIdx.y == 0 && blockIdx.x < 6) {
            int n = blockIdx.x * 256 + t;
            bcat[n] = n < 1024 ? bq[n] : (n < 1280 ? bk[n - 1024] : bv[n - 1280]);
        }
        return;
    }
    const float* src; short* dst; int N;
    switch (z) {
        case 0:  src = Wq; dst = BtQKV;                       N = 1024; break;
        case 1:  src = Wk; dst = BtQKV + (size_t)1024 * 1024; N = 256;  break;
        case 2:  src = Wv; dst = BtQKV + (size_t)1280 * 1024; N = 256;  break;
        default: src = Wo; dst = WoT;                         N = 1024; break;
    }
    const int n0 = blockIdx.x * 64;
    if (n0 >= N) return;
    const int k0 = blockIdx.y * 64;
    __shared__ short Ts[64][68];
    const int r = t >> 4, c4 = (t & 15) * 4;
    #pragma unroll
    for (int i = 0; i < 4; ++i) {
        int k = r + i * 16;
        float4 v = *(const float4*)(src + (size_t)(k0 + k) * N + n0 + c4);
        Ts[c4 + 0][k] = f2bf(v.x);
        Ts[c4 + 1][k] = f2bf(v.y);
        Ts[c4 + 2][k] = f2bf(v.z);
        Ts[c4 + 3][k] = f2bf(v.w);
    }
    __syncthreads();
    #pragma unroll
    for (int i = 0; i < 4; ++i) {
        int n = r + i * 16;
        short4v o = *(short4v*)&Ts[n][c4];
        *(short4v*)(dst + (size_t)(n0 + n) * 1024 + k0 + c4) = o;
    }
}

// ---------------------------------------------------------------------------
// bf16 MFMA GEMM (round-2/6 measured config): 128x128 tile, BK=64, 4 waves,
// reg-staged + XOR slot-swizzle. QKV V-region blocks (bn>=1280) write V^T.
// ---------------------------------------------------------------------------
template <bool BF16_OUT>
__global__ __launch_bounds__(256) void gemm_kernel(
    const short* __restrict__ A, const short* __restrict__ Bt,
    const float* __restrict__ bias, void* __restrict__ Cv,
    short* __restrict__ VtG, int ldc)
{
    __shared__ short As[128 * 64];
    __shared__ short Bs[128 * 64];
    const int t = threadIdx.x;
    const int l = t & 63;
    const int w = t >> 6;
    const int bm = blockIdx.y * 128, bn = blockIdx.x * 128;
    const int wr = (w >> 1) * 64, wc = (w & 1) * 64;
    const int lr = l & 15, lg = l >> 4;

    f32x4 acc[4][4] = {};
    bf16x8 ra[4], rb[4];

    #pragma unroll
    for (int i = 0; i < 4; ++i) {
        int u = t + 256 * i, row = u >> 3, s = u & 7;
        ra[i] = *(const bf16x8*)(A  + (size_t)(bm + row) * 1024 + s * 8);
        rb[i] = *(const bf16x8*)(Bt + (size_t)(bn + row) * 1024 + s * 8);
    }

    for (int k0 = 0; k0 < 1024; k0 += 64) {
        __syncthreads();
        #pragma unroll
        for (int i = 0; i < 4; ++i) {
            int u = t + 256 * i, row = u >> 3, s = u & 7;
            int sd = s ^ (row & 7);
            *(bf16x8*)(&As[row * 64 + sd * 8]) = ra[i];
            *(bf16x8*)(&Bs[row * 64 + sd * 8]) = rb[i];
        }
        if (k0 + 64 < 1024) {
            #pragma unroll
            for (int i = 0; i < 4; ++i) {
                int u = t + 256 * i, row = u >> 3, s = u & 7;
                ra[i] = *(const bf16x8*)(A  + (size_t)(bm + row) * 1024 + k0 + 64 + s * 8);
                rb[i] = *(const bf16x8*)(Bt + (size_t)(bn + row) * 1024 + k0 + 64 + s * 8);
            }
        }
        __syncthreads();
        #pragma unroll
        for (int tt = 0; tt < 2; ++tt) {
            bf16x8 af[4], bfr[4];
            #pragma unroll
            for (int mi = 0; mi < 4; ++mi) {
                int m = wr + mi * 16 + lr;
                af[mi]  = *(const bf16x8*)(&As[m * 64 + ((tt * 4 + lg) ^ (m & 7)) * 8]);
                int n = wc + mi * 16 + lr;
                bfr[mi] = *(const bf16x8*)(&Bs[n * 64 + ((tt * 4 + lg) ^ (n & 7)) * 8]);
            }
            #pragma unroll
            for (int mi = 0; mi < 4; ++mi)
                #pragma unroll
                for (int ni = 0; ni < 4; ++ni)
                    acc[mi][ni] = __builtin_amdgcn_mfma_f32_16x16x32_bf16(
                        af[mi], bfr[ni], acc[mi][ni], 0, 0, 0);
        }
    }

    if constexpr (BF16_OUT) {
        if (bn >= 1280) {          // V-region: write V^T[b][kvh][d][kv]
            #pragma unroll
            for (int ni = 0; ni < 4; ++ni) {
                int n = bn + wc + ni * 16 + lr;
                int vcol = n - 1280, kvh = vcol >> 6, d = vcol & 63;
                float bv = bias[n];
                #pragma unroll
                for (int mi = 0; mi < 4; ++mi) {
                    int m = bm + wr + mi * 16 + lg * 4;
                    int b = m >> 11, kv = m & 2047;
                    short4v ov;
                    ov.x = f2bf(acc[mi][ni][0] + bv);
                    ov.y = f2bf(acc[mi][ni][1] + bv);
                    ov.z = f2bf(acc[mi][ni][2] + bv);
                    ov.w = f2bf(acc[mi][ni][3] + bv);
                    *(short4v*)(VtG + ((size_t)(b * 4 + kvh) * 64 + d) * 2048 + kv) = ov;
                }
            }
            return;
        }
    }
    #pragma unroll
    for (int ni = 0; ni < 4; ++ni) {
        int n = bn + wc + ni * 16 + lr;
        float bv = bias[n];
        #pragma unroll
        for (int mi = 0; mi < 4; ++mi) {
            #pragma unroll
            for (int r = 0; r < 4; ++r) {
                int m = bm + wr + mi * 16 + lg * 4 + r;
                float v = acc[mi][ni][r] + bv;
                if constexpr (BF16_OUT)
                    ((short*)Cv)[(size_t)m * ldc + n] = f2bf(v);
                else
                    ((float*)Cv)[(size_t)m * ldc + n] = v;
            }
        }
    }
}

// ---------------------------------------------------------------------------
// Flash causal GQA attention — KVBLK=128: halves per-kv fixed costs (barriers,
// max-reduce, rescale, prefetch setup) vs KVBLK=64; MFMA per kv unchanged.
// Swapped QK^T (lane owns q=lane&15), lane-local softmax, defer-max.
// PAIRED q-tiles (qb, 31-qb): tiles(qb)+tiles(31-qb) = 17 for every pair ->
// deterministic balance (un-pairing refuted twice: r4 tail, r9 qb-aliasing).
// Only the LAST kv-tile needs masking (2nd-to-last always ends < q0).
// LDS 56KB -> 2 blocks/CU (same as KVBLK=64 which was LDS-capped too).
// ---------------------------------------------------------------------------
__global__ __launch_bounds__(256) void attn_kernel(
    const short* __restrict__ QK, const short* __restrict__ VtG,
    short* __restrict__ Aout)
{
    __shared__ short Qs[64 * 64];        // 8KB  [q][d]   swizzled
    __shared__ short Ks[128 * 64];       // 16KB [kv][d]  swizzled
    __shared__ short Vt[64 * 128];       // 16KB [d][kv]  swizzled (16 slots/row)
    __shared__ short Ps[4 * 16 * 128];   // 16KB per-wave [q][kv]

    const int t = threadIdx.x, l = t & 63, w = t >> 6;
    const int h = blockIdx.y, b = blockIdx.z;
    const int kvh = h >> 2;               // jnp.repeat: h // N_GROUPS
    const int lr = l & 15, lg = l >> 4;
    const float SCL = 0.125f * 1.44269504f;   // 1/sqrt(64) * log2(e)

    const size_t baseQ  = (size_t)(b * SEQ) * LDQK + h * 64;
    const size_t baseK  = (size_t)(b * SEQ) * LDQK + 1024 + kvh * 64;
    const size_t baseVt = (size_t)(b * 4 + kvh) * (64 * 2048);

    for (int pi = 0; pi < 2; ++pi) {
        const int qb = pi ? (31 - (int)blockIdx.x) : (int)blockIdx.x;
        const int q0 = qb * 64;
        const int nt = (qb + 2) >> 1;     // ceil((qb+1)*64 / 128)
        __syncthreads();   // prev pair's reads of LDS complete

        // ---- stage Q tile (swizzled) ----
        #pragma unroll
        for (int i = 0; i < 2; ++i) {
            int u = t + 256 * i, row = u >> 3, s = u & 7;
            bf16x8 v = *(const bf16x8*)(QK + baseQ + (size_t)(q0 + row) * LDQK + s * 8);
            *(bf16x8*)(&Qs[row * 64 + (s ^ (row & 7)) * 8]) = v;
        }
        // ---- prefetch K,V^T tile kb=0 (K: 128x64, V^T: 64x128) ----
        bf16x8 rk[4], rv[4];
        #pragma unroll
        for (int i = 0; i < 4; ++i) {
            int u = t + 256 * i;
            int krow = u >> 3, ks = u & 7;
            rk[i] = *(const bf16x8*)(QK + baseK + (size_t)krow * LDQK + ks * 8);
            int vrow = u >> 4, vs = u & 15;
            rv[i] = *(const bf16x8*)(VtG + baseVt + (size_t)vrow * 2048 + vs * 8);
        }
        __syncthreads();

        // ---- Q fragments (B-operand: lane holds q=lane&15, d-chunk lg*8) ----
        bf16x8 qf[2];
        #pragma unroll
        for (int tt = 0; tt < 2; ++tt) {
            int q = w * 16 + lr;
            qf[tt] = *(const bf16x8*)(&Qs[q * 64 + ((tt * 4 + lg) ^ (lr & 7)) * 8]);
        }

        float m_i = -INFINITY, l_i = 0.f;
        f32x4 o[4];
        #pragma unroll
        for (int ni = 0; ni < 4; ++ni) o[ni] = (f32x4){0.f, 0.f, 0.f, 0.f};

        const int qg = q0 + w * 16 + lr;   // this lane's global q row

        for (int kb = 0; kb < nt; ++kb) {
            __syncthreads();
            // ---- commit staged K [kv][d] and V^T [d][kv] (swizzled) ----
            #pragma unroll
            for (int i = 0; i < 4; ++i) {
                int u = t + 256 * i;
                int krow = u >> 3, ks = u & 7;
                *(bf16x8*)(&Ks[krow * 64 + ((ks ^ (krow & 7)) * 8)]) = rk[i];
                int vrow = u >> 4, vs = u & 15;
                *(bf16x8*)(&Vt[vrow * 128 + ((vs ^ (vrow & 7)) * 8)]) = rv[i];
            }
            // ---- prefetch next tile (in flight under this iter's compute) ----
            if (kb + 1 < nt) {
                int kn = (kb + 1) * 128;
                #pragma unroll
                for (int i = 0; i < 4; ++i) {
                    int u = t + 256 * i;
                    int krow = u >> 3, ks = u & 7;
                    rk[i] = *(const bf16x8*)(QK + baseK + (size_t)(kn + krow) * LDQK + ks * 8);
                    int vrow = u >> 4, vs = u & 15;
                    rv[i] = *(const bf16x8*)(VtG + baseVt + (size_t)vrow * 2048 + kn + vs * 8);
                }
            }
            __syncthreads();

            // ---- S^T = K @ Q^T : lane holds q=lr, kv = ni*16 + lg*4 + r ----
            f32x4 sf[8];
            #pragma unroll
            for (int ni = 0; ni < 8; ++ni) sf[ni] = (f32x4){0.f, 0.f, 0.f, 0.f};
            __builtin_amdgcn_s_setprio(1);
            #pragma unroll
            for (int tt = 0; tt < 2; ++tt) {
                #pragma unroll
                for (int ni = 0; ni < 8; ++ni) {
                    int kvr = ni * 16 + lr;
                    bf16x8 kf = *(const bf16x8*)(&Ks[kvr * 64 + ((tt * 4 + lg) ^ (lr & 7)) * 8]);
                    sf[ni] = __builtin_amdgcn_mfma_f32_16x16x32_bf16(kf, qf[tt], sf[ni], 0, 0, 0);
                }
            }
            __builtin_amdgcn_s_setprio(0);

            // ---- scale (+ causal mask on last tile only) ----
            float p[8][4];
            #pragma unroll
            for (int ni = 0; ni < 8; ++ni)
                #pragma unroll
                for (int r = 0; r < 4; ++r)
                    p[ni][r] = sf[ni][r] * SCL;
            if (kb == nt - 1) {
                #pragma unroll
                for (int ni = 0; ni < 8; ++ni)
                    #pragma unroll
                    for (int r = 0; r < 4; ++r)
                        if (kb * 128 + ni * 16 + lg * 4 + r > qg)
                            p[ni][r] = -INFINITY;
            }

            // ---- lane-local online softmax with defer-max (THR=8 log2) ----
            float rm = -INFINITY;
            #pragma unroll
            for (int ni = 0; ni < 8; ++ni)
                rm = fmaxf(rm, fmaxf(fmaxf(p[ni][0], p[ni][1]),
                                     fmaxf(p[ni][2], p[ni][3])));
            rm = fmaxf(rm, __shfl_xor(rm, 16));
            rm = fmaxf(rm, __shfl_xor(rm, 32));
            if (__any(rm > m_i + 8.0f)) {
                float mnew = fmaxf(m_i, rm);
                float corr = exp2f(m_i - mnew);   // 0 on first tile
                l_i *= corr;
                #pragma unroll
                for (int ni = 0; ni < 4; ++ni) o[ni] *= corr;
                m_i = mnew;
            }
            float rs = 0.f;
            #pragma unroll
            for (int ni = 0; ni < 8; ++ni) {
                #pragma unroll
                for (int r = 0; r < 4; ++r) {
                    float pv = exp2f(p[ni][r] - m_i);
                    p[ni][r] = pv;
                    rs += pv;
                }
                // pack P (4 bf16 = 8B store) into swizzled Ps[q][kv]
                int slot = (ni * 2 + (lg >> 1)) ^ (lr & 7);
                uint2 pk;
                pk.x = pack_bf16(p[ni][0], p[ni][1]);
                pk.y = pack_bf16(p[ni][2], p[ni][3]);
                *(uint2*)(&Ps[w * 2048 + lr * 128 + slot * 8 + (lg & 1) * 4]) = pk;
            }
            rs += __shfl_xor(rs, 16);
            rs += __shfl_xor(rs, 32);
            l_i += rs;

            // ---- O^T += V^T @ P^T (4 kv-chunks of 32) ----
            __builtin_amdgcn_s_setprio(1);
            #pragma unroll
            for (int tt = 0; tt < 4; ++tt) {
                bf16x8 pf = *(const bf16x8*)(&Ps[w * 2048 + lr * 128 + ((tt * 4 + lg) ^ (lr & 7)) * 8]);
                #pragma unroll
                for (int ni = 0; ni < 4; ++ni) {
                    int d = ni * 16 + lr;
                    bf16x8 vf = *(const bf16x8*)(&Vt[d * 128 + ((tt * 4 + lg) ^ (d & 7)) * 8]);
                    o[ni] = __builtin_amdgcn_mfma_f32_16x16x32_bf16(vf, pf, o[ni], 0, 0, 0);
                }
            }
            __builtin_amdgcn_s_setprio(0);
        }

        // ---- normalize + store (lane writes 4x 8B runs on its q row) ----
        float inv = 1.0f / l_i;
        const size_t orow = (size_t)(b * SEQ + qg) * D_MODEL + h * 64;
        #pragma unroll
        for (int ni = 0; ni < 4; ++ni) {
            short4v ov;
            ov.x = f2bf(o[ni][0] * inv);
            ov.y = f2bf(o[ni][1] * inv);
            ov.z = f2bf(o[ni][2] * inv);
            ov.w = f2bf(o[ni][3] * inv);
            *(short4v*)(Aout + orow + ni * 16 + lg * 4) = ov;
        }
    }
}

// ---------------------------------------------------------------------------
extern "C" void kernel_launch(void* const* d_in, const int* in_sizes, int n_in,
                              void* d_out, int out_size, void* d_ws, size_t ws_size,
                              hipStream_t stream) {
    const float* x  = (const float*)d_in[0];
    const float* Wq = (const float*)d_in[1];
    const float* bq = (const float*)d_in[2];
    const float* Wk = (const float*)d_in[3];
    const float* bk = (const float*)d_in[4];
    const float* Wv = (const float*)d_in[5];
    const float* bv = (const float*)d_in[6];
    const float* Wo = (const float*)d_in[7];
    const float* bo = (const float*)d_in[8];
    float* out = (float*)d_out;

    // ws (shorts): xb | BtQKV | WoT | QK(stride1280) | VtG | Abuf | bcat(f32)
    short* xb    = (short*)d_ws;
    short* BtQKV = xb    + (size_t)MROWS * D_MODEL;
    short* WoT   = BtQKV + (size_t)1536 * 1024;
    short* QKbuf = WoT   + (size_t)1024 * 1024;
    short* VtG   = QKbuf + (size_t)MROWS * LDQK;
    short* Abuf  = VtG   + (size_t)BATCH * KV_HEADS * 64 * 2048;
    float* bcat  = (float*)(Abuf + (size_t)MROWS * D_MODEL);

    dim3 blk(256);
    convert_bf16_kernel<<<dim3(MROWS * D_MODEL / 4 / 256), blk, 0, stream>>>(
        x, xb, MROWS * D_MODEL / 4);
    prep_kernel<<<dim3(16, 16, 5), blk, 0, stream>>>(
        Wq, Wk, Wv, Wo, bq, bk, bv, BtQKV, WoT, bcat);
    // fused QKV projection: Q,K -> QKbuf (ldc=1280); V -> VtG transposed
    gemm_kernel<true><<<dim3(12, MROWS / 128), blk, 0, stream>>>(
        xb, BtQKV, bcat, QKbuf, VtG, LDQK);
    attn_kernel<<<dim3(16, N_HEADS, BATCH), blk, 0, stream>>>(QKbuf, VtG, Abuf);
    gemm_kernel<false><<<dim3(8, MROWS / 128), blk, 0, stream>>>(
        Abuf, WoT, bo, out, nullptr, 1024);
}